// Round 1
// baseline (920.186 us; speedup 1.0000x reference)
//
#include <hip/hip_runtime.h>
#include <stdint.h>

#define NT 256        // threads per block
#define NV 16         // uint4 (16B) vectors per thread -> 64 elements/thread
#define PART 16384    // elements per partition
#define KSEL 32u      // top-k

// Order-preserving float->uint transform: larger float <=> larger uint.
__device__ __forceinline__ uint32_t xform(uint32_t u) {
    return (u & 0x80000000u) ? ~u : (u | 0x80000000u);
}

__global__ __launch_bounds__(NT, 4) void topk_scatter_kernel(
        const uint32_t* __restrict__ x, uint32_t* __restrict__ out) {
    __shared__ uint32_t hist[256];
    __shared__ uint32_t sh_prefix, sh_krem, sh_eq, sh_tiecnt;
    __shared__ uint16_t tie_idx[256];

    const size_t base = (size_t)blockIdx.x * (size_t)PART;
    const uint4* __restrict__ xin = (const uint4*)(x + base);
    uint4* __restrict__ xout = (uint4*)(out + base);
    const int t = threadIdx.x;

    // ---- Load 64 elements/thread into registers, coalesced, and transform ----
    uint4 k[NV];
#pragma unroll
    for (int i = 0; i < NV; ++i) k[i] = xin[t + NT * i];
#pragma unroll
    for (int i = 0; i < NV; ++i) {
        k[i].x = xform(k[i].x);
        k[i].y = xform(k[i].y);
        k[i].z = xform(k[i].z);
        k[i].w = xform(k[i].w);
    }

    // ---- 4-pass MSB radix select for the exact 32nd-largest key ----
    uint32_t prefix = 0;   // known high bits of T (low bits zero)
    uint32_t krem = KSEL;  // rank remaining within elements matching prefix

#pragma unroll
    for (int pass = 0; pass < 4; ++pass) {
        const int shift = 24 - 8 * pass;
        hist[t] = 0;
        __syncthreads();

        if (pass == 0) {
#pragma unroll
            for (int i = 0; i < NV; ++i) {
                atomicAdd(&hist[k[i].x >> 24], 1u);
                atomicAdd(&hist[k[i].y >> 24], 1u);
                atomicAdd(&hist[k[i].z >> 24], 1u);
                atomicAdd(&hist[k[i].w >> 24], 1u);
            }
        } else {
            const uint32_t hs = (uint32_t)(shift + 8);
            const uint32_t pfx = prefix >> hs;
#pragma unroll
            for (int i = 0; i < NV; ++i) {
                uint32_t u;
                u = k[i].x; if ((u >> hs) == pfx) atomicAdd(&hist[(u >> shift) & 255u], 1u);
                u = k[i].y; if ((u >> hs) == pfx) atomicAdd(&hist[(u >> shift) & 255u], 1u);
                u = k[i].z; if ((u >> hs) == pfx) atomicAdd(&hist[(u >> shift) & 255u], 1u);
                u = k[i].w; if ((u >> hs) == pfx) atomicAdd(&hist[(u >> shift) & 255u], 1u);
            }
        }
        __syncthreads();

        // Wave 0: suffix-scan 256 buckets (4 per lane + shuffle scan), pick the
        // bucket where the cumulative count from the top crosses krem.
        if (t < 64) {
            uint32_t h0 = hist[4 * t + 0], h1 = hist[4 * t + 1];
            uint32_t h2 = hist[4 * t + 2], h3 = hist[4 * t + 3];
            uint32_t s3 = h3, s2 = h2 + s3, s1 = h1 + s2, s0 = h0 + s1;
            uint32_t S = s0;  // inclusive suffix sum of group totals across lanes
#pragma unroll
            for (int off = 1; off < 64; off <<= 1) {
                int src = t + off;
                uint32_t o = __shfl(S, (src < 64) ? src : t);
                if (src < 64) S += o;
            }
            uint32_t Sx = __shfl(S, (t < 63) ? (t + 1) : t);  // exclusive (groups > t)
            if (t == 63) Sx = 0;
            uint32_t scs[5] = { s0 + Sx, s1 + Sx, s2 + Sx, s3 + Sx, Sx };
            uint32_t hh[4] = { h0, h1, h2, h3 };
#pragma unroll
            for (int j = 0; j < 4; ++j) {
                if (scs[j] >= krem && scs[j + 1] < krem) {   // unique crossing
                    sh_prefix = prefix | ((uint32_t)(4 * t + j) << shift);
                    sh_krem = krem - scs[j + 1];
                    sh_eq = hh[j];
                }
            }
        }
        __syncthreads();
        prefix = sh_prefix;
        krem = sh_krem;
    }

    const uint32_t T = prefix;      // exact key of the 32nd-largest value
    const uint32_t r = krem;        // how many elements equal to T are in top-32
    const uint32_t cnt_eq = sh_eq;  // total elements equal to T
    const bool need_order = (cnt_eq != r);  // boundary tie: must pick lowest indices

    // ---- Rare path: collect tie indices so we can rank them by index ----
    uint32_t ntie = 0;
    if (need_order) {
        if (t == 0) sh_tiecnt = 0;
        __syncthreads();
#pragma unroll
        for (int i = 0; i < NV; ++i) {
            const uint32_t e0 = 4u * (uint32_t)(t + NT * i);
            uint32_t p;
            if (k[i].x == T) { p = atomicAdd(&sh_tiecnt, 1u); if (p < 256u) tie_idx[p] = (uint16_t)(e0 + 0u); }
            if (k[i].y == T) { p = atomicAdd(&sh_tiecnt, 1u); if (p < 256u) tie_idx[p] = (uint16_t)(e0 + 1u); }
            if (k[i].z == T) { p = atomicAdd(&sh_tiecnt, 1u); if (p < 256u) tie_idx[p] = (uint16_t)(e0 + 2u); }
            if (k[i].w == T) { p = atomicAdd(&sh_tiecnt, 1u); if (p < 256u) tie_idx[p] = (uint16_t)(e0 + 3u); }
        }
        __syncthreads();
        ntie = sh_tiecnt;
        if (ntie > 256u) ntie = 256u;
    }

    // ---- Write pass: coalesced uint4 stores; selected -> relu(value), else 0 ----
#pragma unroll
    for (int i = 0; i < NV; ++i) {
        const uint32_t e0 = 4u * (uint32_t)(t + NT * i);
        uint4 o;
        uint32_t us[4] = { k[i].x, k[i].y, k[i].z, k[i].w };
        uint32_t os[4];
#pragma unroll
        for (int c = 0; c < 4; ++c) {
            const uint32_t u = us[c];
            bool sel;
            if (u > T) {
                sel = true;
            } else if (u == T) {
                if (!need_order) {
                    sel = true;
                } else {
                    const uint32_t eidx = e0 + (uint32_t)c;
                    uint32_t rank = 0;
                    for (uint32_t q = 0; q < ntie; ++q) rank += (tie_idx[q] < eidx) ? 1u : 0u;
                    sel = (rank < r);
                }
            } else {
                sel = false;
            }
            // relu: original float is non-negative iff u >= 0x80000000; its bits
            // are u ^ 0x80000000. Negative (or unselected) -> 0.0f bits.
            os[c] = (sel && (u & 0x80000000u)) ? (u ^ 0x80000000u) : 0u;
        }
        o.x = os[0]; o.y = os[1]; o.z = os[2]; o.w = os[3];
        xout[t + NT * i] = o;
    }
}

extern "C" void kernel_launch(void* const* d_in, const int* in_sizes, int n_in,
                              void* d_out, int out_size, void* d_ws, size_t ws_size,
                              hipStream_t stream) {
    const uint32_t* x = (const uint32_t*)d_in[0];
    uint32_t* out = (uint32_t*)d_out;
    const int nparts = in_sizes[0] / PART;  // 4096 rows * 2 partitions = 8192
    topk_scatter_kernel<<<dim3(nparts), dim3(NT), 0, stream>>>(x, out);
}

// Round 3
// 849.656 us; speedup vs baseline: 1.0830x; 1.0830x over previous
//
#include <hip/hip_runtime.h>
#include <stdint.h>

#define NT 256        // threads per block
#define NV 16         // 16B vectors per thread -> 64 elements/thread
#define PART 16384    // elements per partition
#define KSEL 32u      // top-k
#define CAP 2048      // candidate-list capacity (fallback beyond this)

// Native clang vector type: __builtin_nontemporal_* accepts these (HIP's uint4
// class type is rejected).
typedef uint32_t u32x4 __attribute__((ext_vector_type(4)));

// Order-preserving float->uint transform: larger float <=> larger uint.
__device__ __forceinline__ uint32_t xform(uint32_t u) {
    return (u & 0x80000000u) ? ~u : (u | 0x80000000u);
}

__global__ __launch_bounds__(NT, 4) void topk_scatter_kernel(
        const uint32_t* __restrict__ x, uint32_t* __restrict__ out) {
    __shared__ uint32_t maxima[NT];      // per-thread maxima
    __shared__ uint32_t cand_key[CAP];   // candidate keys (>= pivot)
    __shared__ uint16_t cand_idx[CAP];   // candidate indices within partition
    __shared__ uint32_t red[8];          // cross-wave reduction scratch
    __shared__ uint32_t sh_P, sh_cnt, sh_T, sh_gt, sh_eq;

    const size_t base = (size_t)blockIdx.x * (size_t)PART;
    const u32x4* __restrict__ xin = (const u32x4*)(x + base);
    u32x4* __restrict__ xout = (u32x4*)(out + base);
    const int t = threadIdx.x;

    // ---- Load 64 elements/thread into registers (coalesced, streaming) ----
    u32x4 k[NV];
#pragma unroll
    for (int i = 0; i < NV; ++i) k[i] = __builtin_nontemporal_load(&xin[t + NT * i]);

    // ---- Transform to order-preserving keys; track per-thread max ----
    uint32_t mymax = 0;
#pragma unroll
    for (int i = 0; i < NV; ++i) {
#pragma unroll
        for (int c = 0; c < 4; ++c) {
            k[i][c] = xform(k[i][c]);
            mymax = max(mymax, k[i][c]);
        }
    }

    if (t == 0) { sh_P = 0xFFFFFFFFu; sh_cnt = 0; sh_T = 0xFFFFFFFFu; sh_gt = 0; sh_eq = 0; }
    maxima[t] = mymax;
    __syncthreads();

    // ---- Pivot P = exact 32nd-largest of the 256 per-thread maxima.
    // Broadcast LDS reads (all lanes read same address) -> conflict-free.
    uint32_t cgt = 0;
#pragma unroll 16
    for (int j = 0; j < NT; ++j) cgt += (maxima[j] > mymax) ? 1u : 0u;
    if (cgt < KSEL) atomicMin(&sh_P, mymax);  // P = min of top-32 maxima
    __syncthreads();
    const uint32_t P = sh_P;
    // Guarantee: >=32 threads have max >= P, each contributes >=1 element >= P,
    // so count(elements >= P) >= 32 and therefore T (32nd largest) >= P.

    // ---- Gather candidates (key >= P) into LDS; expected ~30-60 for N(0,1) ----
#pragma unroll
    for (int i = 0; i < NV; ++i) {
        const uint32_t e0 = 4u * (uint32_t)(t + NT * i);
#pragma unroll
        for (int c = 0; c < 4; ++c) {
            const uint32_t u = k[i][c];
            if (u >= P) {
                uint32_t p = atomicAdd(&sh_cnt, 1u);
                if (p < CAP) { cand_key[p] = u; cand_idx[p] = (uint16_t)(e0 + (uint32_t)c); }
            }
        }
    }
    __syncthreads();
    uint32_t m = sh_cnt;

    uint32_t T, r;
    bool need_order;

    if (m <= CAP) {
        // ---- Exact select among candidates: T = min{key : count(keys > key) < 32} ----
        for (uint32_t j = t; j < m; j += NT) {
            const uint32_t kj = cand_key[j];
            uint32_t c = 0;
            for (uint32_t i2 = 0; i2 < m; ++i2) c += (cand_key[i2] > kj) ? 1u : 0u;
            if (c < KSEL) atomicMin(&sh_T, kj);
        }
        __syncthreads();
        T = sh_T;
        uint32_t lgt = 0, leq = 0;
        for (uint32_t j = t; j < m; j += NT) {
            const uint32_t kj = cand_key[j];
            lgt += (kj > T) ? 1u : 0u;
            leq += (kj == T) ? 1u : 0u;
        }
        if (lgt) atomicAdd(&sh_gt, lgt);
        if (leq) atomicAdd(&sh_eq, leq);
        __syncthreads();
        r = KSEL - sh_gt;               // ties to include
        need_order = (sh_eq != r);      // boundary tie needing index order
        // cand list already holds every element == T (all are >= P)
    } else {
        // ---- Cold fallback: 32-round bitwise search (exact, contention-free) ----
        uint32_t pref = 0;
        for (int b = 31; b >= 0; --b) {
            const uint32_t trial = pref | (1u << b);
            uint32_t lc = 0;
#pragma unroll
            for (int i = 0; i < NV; ++i) {
#pragma unroll
                for (int c = 0; c < 4; ++c) lc += (k[i][c] >= trial) ? 1u : 0u;
            }
#pragma unroll
            for (int off = 32; off; off >>= 1) lc += __shfl_down(lc, off);
            if ((t & 63) == 0) red[t >> 6] = lc;
            __syncthreads();
            if (t == 0) sh_gt = red[0] + red[1] + red[2] + red[3];
            __syncthreads();
            if (sh_gt >= KSEL) pref = trial;
            // next iteration's red[] writes are ordered by its own __syncthreads
        }
        T = pref;
        // count > T and == T over registers
        uint32_t lgt = 0, leq = 0;
#pragma unroll
        for (int i = 0; i < NV; ++i) {
#pragma unroll
            for (int c = 0; c < 4; ++c) {
                lgt += (k[i][c] > T) ? 1u : 0u;
                leq += (k[i][c] == T) ? 1u : 0u;
            }
        }
#pragma unroll
        for (int off = 32; off; off >>= 1) { lgt += __shfl_down(lgt, off); leq += __shfl_down(leq, off); }
        if ((t & 63) == 0) { red[t >> 6] = lgt; red[4 + (t >> 6)] = leq; }
        __syncthreads();
        if (t == 0) {
            sh_gt = red[0] + red[1] + red[2] + red[3];
            sh_eq = red[4] + red[5] + red[6] + red[7];
        }
        __syncthreads();
        r = KSEL - sh_gt;
        need_order = (sh_eq != r);
        if (need_order) {
            if (t == 0) sh_cnt = 0;
            __syncthreads();
#pragma unroll
            for (int i = 0; i < NV; ++i) {
                const uint32_t e0 = 4u * (uint32_t)(t + NT * i);
#pragma unroll
                for (int c = 0; c < 4; ++c) {
                    if (k[i][c] == T) {
                        uint32_t p = atomicAdd(&sh_cnt, 1u);
                        if (p < CAP) { cand_key[p] = T; cand_idx[p] = (uint16_t)(e0 + (uint32_t)c); }
                    }
                }
            }
            __syncthreads();
            m = sh_cnt < CAP ? sh_cnt : CAP;
        } else {
            m = 0;
        }
    }

    // ---- Write pass: coalesced streaming 16B stores ----
#pragma unroll
    for (int i = 0; i < NV; ++i) {
        const uint32_t e0 = 4u * (uint32_t)(t + NT * i);
        u32x4 o;
#pragma unroll
        for (int c = 0; c < 4; ++c) {
            const uint32_t u = k[i][c];
            bool sel;
            if (u > T) {
                sel = true;
            } else if (u == T) {
                if (!need_order) {
                    sel = true;
                } else {
                    const uint32_t eidx = e0 + (uint32_t)c;
                    uint32_t rank = 0;
                    for (uint32_t j = 0; j < m; ++j)
                        rank += (cand_key[j] == T && (uint32_t)cand_idx[j] < eidx) ? 1u : 0u;
                    sel = (rank < r);   // keep the r lowest-indexed ties
                }
            } else {
                sel = false;
            }
            // relu: original float >= 0 iff key >= 0x80000000; bits = key ^ 0x80000000.
            o[c] = (sel && (u & 0x80000000u)) ? (u ^ 0x80000000u) : 0u;
        }
        __builtin_nontemporal_store(o, &xout[t + NT * i]);
    }
}

extern "C" void kernel_launch(void* const* d_in, const int* in_sizes, int n_in,
                              void* d_out, int out_size, void* d_ws, size_t ws_size,
                              hipStream_t stream) {
    const uint32_t* x = (const uint32_t*)d_in[0];
    uint32_t* out = (uint32_t*)d_out;
    const int nparts = in_sizes[0] / PART;  // 4096 rows * 2 partitions = 8192
    topk_scatter_kernel<<<dim3(nparts), dim3(NT), 0, stream>>>(x, out);
}